// Round 3
// baseline (276.776 us; speedup 1.0000x reference)
//
#include <hip/hip_runtime.h>
#include <math.h>

// Sampler: B=256 rows, V=128256 vocab.
// out[b] = (T[b]==0) ? argmax(logits[b,:])
//                    : argmax(logits[b,:]/T[b] - log(-log1p(-noise[b,:])))
// Log-space Gumbel-max (softmax denom + row-max cancel), all in log2 so each
// log is one HW v_log_f32.
//
// R6 post-mortem: asm-volatile distance-3 pipeline with exact counted
// vmcnt(6) ran for real and changed NOTHING (97.4 -> 95.4 us).  Three
// different schedules all pin at 2.58 TB/s effective with HBM at 20% and
// VALU at 16% -> the cap is a per-CU outstanding-request (MSHR) limit on
// the VGPR-return load path: ~4.2 B/cyc/CU = lines*64B/latency.  More SW
// ILP cannot add HW tracker entries.
// R7: switch the streaming to global_load_lds (the GEMM DMA path) -- it
// bypasses the VGPR-writeback/L1-return path and demonstrably sustains
// deeper outstanding queues (m97/m218 counted-vmcnt pipelines).
//   - per-wave PRIVATE LDS buffers, no __syncthreads in the stream loop;
//   - sampled: double-buffer, 2 stages (4 loads) in flight, vmcnt(2);
//     greedy: quad-buffer, vmcnt(3);
//   - consume via volatile LDS reads fenced by asm vmcnt + sched_barrier(0)
//     (rule #18: VALU can hoist past inline-asm waitcnt otherwise);
//   - tail stages re-issue with clamped addresses so vmcnt stays exact.

constexpr int TPB    = 512;
constexpr int CHUNKS = 4;
constexpr int WPB    = TPB / 64;   // 8 waves/block

typedef float v4f __attribute__((ext_vector_type(4)));

__device__ __forceinline__ void amax_comb(float v, int i, float& bv, int& bi) {
    // np.argmax semantics: strictly greater wins; ties -> lowest index
    if (v > bv || (v == bv && i < bi)) { bv = v; bi = i; }
}

// key = l*c - log2(-log1p(-u)), c = invT/ln2.  Abs err ~1e-6, far below
// top-1/top-2 Gumbel key gaps.  u==0 -> en=0 -> -inf -> key=+inf, matching
// reference probs/0 = +inf (first-index tie-break both sides).
__device__ __forceinline__ float gumbel_key(float l, float u, float c) {
    // u >= 0.125: 1-u exact on the 2^-24 uniform grid, |log2(1-u)| >= 0.19
    const float w   = 1.0f - u;
    const float enw = __log2f(w) * -0.693147180559945f;   // -log(1-u)
    // u < 0.125: en/u = 1 + u/2 + u^2/3 + ... (trunc err < 6e-6 rel)
    float p = 0.16666667f;
    p = fmaf(p, u, 0.2f);
    p = fmaf(p, u, 0.25f);
    p = fmaf(p, u, 0.33333333f);
    p = fmaf(p, u, 0.5f);
    p = fmaf(p, u, 1.0f);
    const float en = (u < 0.125f) ? p * u : enw;
    return fmaf(l, c, -__log2f(en));
}

// Counted wait on the DMA queue + fence against compiler hoisting consumers.
#define WAITV(N)                                                        \
    asm volatile("s_waitcnt vmcnt(" #N ")" ::: "memory");               \
    __builtin_amdgcn_sched_barrier(0)

__global__ __launch_bounds__(TPB, 8) void sampler_phase1(
    const float* __restrict__ logits,
    const float* __restrict__ temps,
    const float* __restrict__ noise,
    float* __restrict__ ws_val,
    int* __restrict__ ws_idx, int V)
{
    const int chunk = blockIdx.x & (CHUNKS - 1);
    const int b     = blockIdx.x / CHUNKS;
    const int V4    = V >> 2;               // 32064
    const int V4c   = V4 / CHUNKS;          // 8016 (V divisible by 16)
    const int gbase = chunk * V4c;          // this chunk's first float4 index
    const float temp = temps[b];
    const v4f* __restrict__ lg4 =
        (const v4f*)(logits + (size_t)b * V) + gbase;
    const v4f* __restrict__ nz4 =
        (const v4f*)(noise + (size_t)b * V) + gbase;
    const int t    = threadIdx.x;
    const int lane = t & 63;
    const int wave = t >> 6;
    const int last = V4c - 1;
    const int S_tot = (V4c + 63) >> 6;              // 64-float4 stages (126)
    const int kcnt  = (S_tot - wave + WPB - 1) / WPB;  // this wave's stages

    // Per-wave private DMA buffers: [buf][wave][lane].  32 KiB total.
    __shared__ v4f bufA[2][WPB][64];
    __shared__ v4f bufB[2][WPB][64];

    float bv = -INFINITY;
    int   bi = 0x7fffffff;

    if (temp == 0.0f) {
        // Greedy: logits only; quad-buffer across bufA/bufB, vmcnt(3).
        // Tail issues re-load a clamped stage so vmcnt counting stays exact.
#define G_PTR(B4) ((B4) < 2 ? &bufA[(B4)][wave][0] : &bufB[(B4) - 2][wave][0])
#define G_ISSUE(K)                                                      \
        {                                                               \
            const int s_ = min(wave + WPB * (K), S_tot - 1);            \
            const int f_ = min(s_ * 64 + lane, last);                   \
            __builtin_amdgcn_global_load_lds((const void*)(lg4 + f_),   \
                                             (void*)G_PTR((K) & 3),     \
                                             16, 0, 0);                 \
        }
        G_ISSUE(0); G_ISSUE(1); G_ISSUE(2);
        for (int k = 0; k < kcnt; ++k) {
            WAITV(3);
            const int s = wave + WPB * k;
            volatile const v4f* p =
                ((volatile const v4f*)G_PTR(k & 3)) + lane;
            const v4f l = *p;
            __builtin_amdgcn_sched_barrier(0);
            G_ISSUE(k + 3);
            const int f = s * 64 + lane;
            if (f < V4c) {
                const int base = (gbase + f) << 2;
                if (l.x > bv) { bv = l.x; bi = base;     }
                if (l.y > bv) { bv = l.y; bi = base + 1; }
                if (l.z > bv) { bv = l.z; bi = base + 2; }
                if (l.w > bv) { bv = l.w; bi = base + 3; }
            }
        }
        asm volatile("s_waitcnt vmcnt(0)" ::: "memory");
    } else {
        const float c = (1.0f / temp) * 1.4426950408889634f;  // invT / ln2
        // Sampled: two streams, double-buffer, 2 stages (4 DMAs) in flight.
#define S_ISSUE(K)                                                      \
        {                                                               \
            const int s_ = min(wave + WPB * (K), S_tot - 1);            \
            const int f_ = min(s_ * 64 + lane, last);                   \
            const int b_ = (K) & 1;                                     \
            __builtin_amdgcn_global_load_lds((const void*)(lg4 + f_),   \
                                             (void*)&bufA[b_][wave][0], \
                                             16, 0, 0);                 \
            __builtin_amdgcn_global_load_lds((const void*)(nz4 + f_),   \
                                             (void*)&bufB[b_][wave][0], \
                                             16, 0, 0);                 \
        }
        S_ISSUE(0); S_ISSUE(1);
        for (int k = 0; k < kcnt; ++k) {
            WAITV(2);
            const int s  = wave + WPB * k;
            const int b_ = k & 1;
            volatile const v4f* pL = &bufA[b_][wave][lane];
            volatile const v4f* pU = &bufB[b_][wave][lane];
            const v4f l = *pL;
            const v4f u = *pU;
            __builtin_amdgcn_sched_barrier(0);
            S_ISSUE(k + 2);
            const int f = s * 64 + lane;
            if (f < V4c) {
                const int base = (gbase + f) << 2;
                const float k0 = gumbel_key(l.x, u.x, c);
                const float k1 = gumbel_key(l.y, u.y, c);
                const float k2 = gumbel_key(l.z, u.z, c);
                const float k3 = gumbel_key(l.w, u.w, c);
                if (k0 > bv) { bv = k0; bi = base;     }
                if (k1 > bv) { bv = k1; bi = base + 1; }
                if (k2 > bv) { bv = k2; bi = base + 2; }
                if (k3 > bv) { bv = k3; bi = base + 3; }
            }
        }
        asm volatile("s_waitcnt vmcnt(0)" ::: "memory");
    }

    // wave (64-lane) shuffle reduction, lowest-index tie-break
    #pragma unroll
    for (int off = 32; off > 0; off >>= 1) {
        const float ov = __shfl_down(bv, off);
        const int   oi = __shfl_down(bi, off);
        amax_comb(ov, oi, bv, bi);
    }

    __shared__ float s_v[WPB];
    __shared__ int   s_i[WPB];
    if (lane == 0) { s_v[wave] = bv; s_i[wave] = bi; }
    __syncthreads();
    if (t == 0) {
        #pragma unroll
        for (int w = 1; w < WPB; ++w) amax_comb(s_v[w], s_i[w], bv, bi);
        ws_val[blockIdx.x] = bv;
        ws_idx[blockIdx.x] = bi;
    }
}

__global__ void sampler_phase2(const float* __restrict__ ws_val,
                               const int* __restrict__ ws_idx,
                               int* __restrict__ out, int B)
{
    const int b = blockIdx.x * blockDim.x + threadIdx.x;
    if (b >= B) return;
    float bv = -INFINITY;
    int   bi = 0x7fffffff;
    #pragma unroll
    for (int c = 0; c < CHUNKS; ++c) {
        const float v = ws_val[b * CHUNKS + c];
        const int   i = ws_idx[b * CHUNKS + c];
        // chunk-ascending iteration + strict-> keeps lowest index on ties
        if (v > bv || (v == bv && i < bi)) { bv = v; bi = i; }
    }
    out[b] = bi;
}

extern "C" void kernel_launch(void* const* d_in, const int* in_sizes, int n_in,
                              void* d_out, int out_size, void* d_ws, size_t ws_size,
                              hipStream_t stream) {
    const float* logits = (const float*)d_in[0];   // [B, V] fp32
    const float* temps  = (const float*)d_in[1];   // [B]    fp32
    const float* noise  = (const float*)d_in[2];   // [B, V] fp32
    int* out = (int*)d_out;                        // [B]    int32
    const int B = in_sizes[1];
    const int V = in_sizes[0] / B;

    float* ws_val = (float*)d_ws;                  // [B*CHUNKS]
    int*   ws_idx = (int*)d_ws + (size_t)B * CHUNKS;

    sampler_phase1<<<B * CHUNKS, TPB, 0, stream>>>(logits, temps, noise,
                                                   ws_val, ws_idx, V);
    sampler_phase2<<<(B + 255) / 256, 256, 0, stream>>>(ws_val, ws_idx, out, B);
}

// Round 4
// 248.011 us; speedup vs baseline: 1.1160x; 1.1160x over previous
//
#include <hip/hip_runtime.h>
#include <math.h>

// Sampler: B=256 rows, V=128256 vocab.
// out[b] = (T[b]==0) ? argmax(logits[b,:])
//                    : argmax(logits[b,:]/T[b] - log(-log1p(-noise[b,:])))
// Log-space Gumbel-max (softmax denom + row-max cancel), all in log2 so each
// log is one HW v_log_f32.
//
// R7 post-mortem: the triad is complete --
//   scheduling-invariant (at-use / asm vmcnt(6) depth-3 / global_load_lds DMA
//   all ~96-101us), source-invariant (all-L3-hit dispatches with FETCH~0 run
//   the SAME 97us as 123MB-HBM dispatches), both pipes idle (VALU 17%, HBM
//   16%).  The ~2.5 TB/s wall is a CU-side request-path (TCP/L1) rate limit:
//   ~64 interleaved zero-reuse 1KB-granular streams per CU thrash the 32KiB
//   L1 -- every line is a miss + allocate + evict, and that allocation
//   machinery is a fixed-rate limiter invisible to vmcnt scheduling and
//   indifferent to HBM-vs-L3 service.
// R8: bypass L1 entirely -- __builtin_nontemporal_load (global_load_dwordx4
// nt) on all streaming reads; data has zero intra-dispatch reuse so L1
// allocation is pure overhead.  Scheduling machinery dropped (proven
// irrelevant).  CHUNKS=8/TPB=256 -> 2048 blocks = exactly 8/CU in one round,
// finer greedy/sampled mixing; 2x float4 per lane per stream per iteration.

constexpr int TPB    = 256;
constexpr int CHUNKS = 8;

typedef float v4f __attribute__((ext_vector_type(4)));

__device__ __forceinline__ void amax_comb(float v, int i, float& bv, int& bi) {
    // np.argmax semantics: strictly greater wins; ties -> lowest index
    if (v > bv || (v == bv && i < bi)) { bv = v; bi = i; }
}

// key = l*c - log2(-log1p(-u)), c = invT/ln2.  Abs err ~1e-6, far below
// top-1/top-2 Gumbel key gaps.  u==0 -> en=0 -> -inf -> key=+inf, matching
// reference probs/0 = +inf (first-index tie-break both sides).
__device__ __forceinline__ float gumbel_key(float l, float u, float c) {
    // u >= 0.125: 1-u exact on the 2^-24 uniform grid, |log2(1-u)| >= 0.19
    const float w   = 1.0f - u;
    const float enw = __log2f(w) * -0.693147180559945f;   // -log(1-u)
    // u < 0.125: en/u = 1 + u/2 + u^2/3 + ... (trunc err < 6e-6 rel)
    float p = 0.16666667f;
    p = fmaf(p, u, 0.2f);
    p = fmaf(p, u, 0.25f);
    p = fmaf(p, u, 0.33333333f);
    p = fmaf(p, u, 0.5f);
    p = fmaf(p, u, 1.0f);
    const float en = (u < 0.125f) ? p * u : enw;
    return fmaf(l, c, -__log2f(en));
}

__global__ __launch_bounds__(TPB, 8) void sampler_phase1(
    const float* __restrict__ logits,
    const float* __restrict__ temps,
    const float* __restrict__ noise,
    float* __restrict__ ws_val,
    int* __restrict__ ws_idx, int V)
{
    const int chunk = blockIdx.x & (CHUNKS - 1);
    const int b     = blockIdx.x / CHUNKS;
    const int V4    = V >> 2;               // 32064
    const int V4c   = V4 / CHUNKS;          // 4008 (V divisible by 32)
    const int gbase = chunk * V4c;          // this chunk's first float4 index
    const float temp = temps[b];
    const v4f* __restrict__ lg4 =
        (const v4f*)(logits + (size_t)b * V) + gbase;
    const v4f* __restrict__ nz4 =
        (const v4f*)(noise + (size_t)b * V) + gbase;
    const int t    = threadIdx.x;
    const int last = V4c - 1;
    // two float4 per lane per stream per iteration
    const int NIT  = (V4c + 2 * TPB - 1) / (2 * TPB);   // 8 for V=128256

    float bv = -INFINITY;
    int   bi = 0x7fffffff;

    if (temp == 0.0f) {
        // Greedy: argmax of raw logits, no noise traffic.
        for (int j = 0; j < NIT; ++j) {
            const int f0 = t + j * (2 * TPB);
            const int f1 = f0 + TPB;
            // nt loads: no L1 allocation (zero-reuse stream)
            const v4f a = __builtin_nontemporal_load(lg4 + min(f0, last));
            const v4f bq = __builtin_nontemporal_load(lg4 + min(f1, last));
            if (f0 < V4c) {
                const int base = (gbase + f0) << 2;
                // per-thread indices ascend -> strict > keeps lowest index
                if (a.x > bv) { bv = a.x; bi = base;     }
                if (a.y > bv) { bv = a.y; bi = base + 1; }
                if (a.z > bv) { bv = a.z; bi = base + 2; }
                if (a.w > bv) { bv = a.w; bi = base + 3; }
            }
            if (f1 < V4c) {
                const int base = (gbase + f1) << 2;
                if (bq.x > bv) { bv = bq.x; bi = base;     }
                if (bq.y > bv) { bv = bq.y; bi = base + 1; }
                if (bq.z > bv) { bv = bq.z; bi = base + 2; }
                if (bq.w > bv) { bv = bq.w; bi = base + 3; }
            }
        }
    } else {
        const float c = (1.0f / temp) * 1.4426950408889634f;  // invT / ln2
        for (int j = 0; j < NIT; ++j) {
            const int f0 = t + j * (2 * TPB);
            const int f1 = f0 + TPB;
            const v4f l0 = __builtin_nontemporal_load(lg4 + min(f0, last));
            const v4f u0 = __builtin_nontemporal_load(nz4 + min(f0, last));
            const v4f l1 = __builtin_nontemporal_load(lg4 + min(f1, last));
            const v4f u1 = __builtin_nontemporal_load(nz4 + min(f1, last));
            if (f0 < V4c) {
                const int base = (gbase + f0) << 2;
                const float k0 = gumbel_key(l0.x, u0.x, c);
                const float k1 = gumbel_key(l0.y, u0.y, c);
                const float k2 = gumbel_key(l0.z, u0.z, c);
                const float k3 = gumbel_key(l0.w, u0.w, c);
                if (k0 > bv) { bv = k0; bi = base;     }
                if (k1 > bv) { bv = k1; bi = base + 1; }
                if (k2 > bv) { bv = k2; bi = base + 2; }
                if (k3 > bv) { bv = k3; bi = base + 3; }
            }
            if (f1 < V4c) {
                const int base = (gbase + f1) << 2;
                const float k0 = gumbel_key(l1.x, u1.x, c);
                const float k1 = gumbel_key(l1.y, u1.y, c);
                const float k2 = gumbel_key(l1.z, u1.z, c);
                const float k3 = gumbel_key(l1.w, u1.w, c);
                if (k0 > bv) { bv = k0; bi = base;     }
                if (k1 > bv) { bv = k1; bi = base + 1; }
                if (k2 > bv) { bv = k2; bi = base + 2; }
                if (k3 > bv) { bv = k3; bi = base + 3; }
            }
        }
    }

    // wave (64-lane) shuffle reduction, lowest-index tie-break
    #pragma unroll
    for (int off = 32; off > 0; off >>= 1) {
        const float ov = __shfl_down(bv, off);
        const int   oi = __shfl_down(bi, off);
        amax_comb(ov, oi, bv, bi);
    }

    __shared__ float s_v[TPB / 64];
    __shared__ int   s_i[TPB / 64];
    const int lane = t & 63;
    const int wave = t >> 6;
    if (lane == 0) { s_v[wave] = bv; s_i[wave] = bi; }
    __syncthreads();
    if (t == 0) {
        #pragma unroll
        for (int w = 1; w < TPB / 64; ++w) amax_comb(s_v[w], s_i[w], bv, bi);
        ws_val[blockIdx.x] = bv;
        ws_idx[blockIdx.x] = bi;
    }
}

__global__ void sampler_phase2(const float* __restrict__ ws_val,
                               const int* __restrict__ ws_idx,
                               int* __restrict__ out, int B)
{
    const int b = blockIdx.x * blockDim.x + threadIdx.x;
    if (b >= B) return;
    float bv = -INFINITY;
    int   bi = 0x7fffffff;
    #pragma unroll
    for (int c = 0; c < CHUNKS; ++c) {
        const float v = ws_val[b * CHUNKS + c];
        const int   i = ws_idx[b * CHUNKS + c];
        // chunk-ascending iteration + strict-> keeps lowest index on ties
        if (v > bv || (v == bv && i < bi)) { bv = v; bi = i; }
    }
    out[b] = bi;
}

extern "C" void kernel_launch(void* const* d_in, const int* in_sizes, int n_in,
                              void* d_out, int out_size, void* d_ws, size_t ws_size,
                              hipStream_t stream) {
    const float* logits = (const float*)d_in[0];   // [B, V] fp32
    const float* temps  = (const float*)d_in[1];   // [B]    fp32
    const float* noise  = (const float*)d_in[2];   // [B, V] fp32
    int* out = (int*)d_out;                        // [B]    int32
    const int B = in_sizes[1];
    const int V = in_sizes[0] / B;

    float* ws_val = (float*)d_ws;                  // [B*CHUNKS]
    int*   ws_idx = (int*)d_ws + (size_t)B * CHUNKS;

    sampler_phase1<<<B * CHUNKS, TPB, 0, stream>>>(logits, temps, noise,
                                                   ws_val, ws_idx, V);
    sampler_phase2<<<(B + 255) / 256, 256, 0, stream>>>(ws_val, ws_idx, out, B);
}

// Round 5
// 245.547 us; speedup vs baseline: 1.1272x; 1.0100x over previous
//
#include <hip/hip_runtime.h>
#include <math.h>

// Sampler: B=256 rows, V=128256 vocab.
// out[b] = (T[b]==0) ? argmax(logits[b,:])
//                    : argmax(logits[b,:]/T[b] - log(-log1p(-noise[b,:])))
// Log-space Gumbel-max (softmax denom + row-max cancel), all in log2 so each
// log is one HW v_log_f32.
//
// R8 post-mortem: nt loads (L1-allocate bypass) gave the first real win in
// four rounds: dur 272->248, phase1 ~96 -> ~71us (~3.4 TB/s effective).
// The 2.58 TB/s wall WAS the L1 allocation path -- which also explains why
// R6's deep asm pipeline nulled (depth had nothing to feed behind a fixed-
// rate wall).  fillBufferAligned in the same trace sustains 6.8 TB/s, so
// the fabric has 2x headroom.  With the wall gone, the untested combination
// is nt + guaranteed depth: at-use nt loads only hold 64 B/lane in flight.
// R9: R6's compiler-proof distance-3 asm pipeline (exact counted vmcnt,
// proven emitted) with nt on every load, at the R8 grid (TPB=256, CHUNKS=8,
// 2048 blocks = 8/CU = 32 waves/CU, one round).
//   - sampled: 8 float4 buffers, vmcnt(6) -> 96 B/lane always in flight;
//   - greedy:  4 buffers, vmcnt(3);
//   - sched_barrier(0) after each waitcnt (rule #18);
//   - final vmcnt(0) asm carries all buffers as inputs (liveness pin).

constexpr int TPB    = 256;
constexpr int CHUNKS = 8;

typedef float v4f __attribute__((ext_vector_type(4)));

__device__ __forceinline__ void amax_comb(float v, int i, float& bv, int& bi) {
    // np.argmax semantics: strictly greater wins; ties -> lowest index
    if (v > bv || (v == bv && i < bi)) { bv = v; bi = i; }
}

// key = l*c - log2(-log1p(-u)), c = invT/ln2.  Abs err ~1e-6, far below
// top-1/top-2 Gumbel key gaps.  u==0 -> en=0 -> -inf -> key=+inf, matching
// reference probs/0 = +inf (first-index tie-break both sides).
__device__ __forceinline__ float gumbel_key(float l, float u, float c) {
    // u >= 0.125: 1-u exact on the 2^-24 uniform grid, |log2(1-u)| >= 0.19
    const float w   = 1.0f - u;
    const float enw = __log2f(w) * -0.693147180559945f;   // -log(1-u)
    // u < 0.125: en/u = 1 + u/2 + u^2/3 + ... (trunc err < 6e-6 rel)
    float p = 0.16666667f;
    p = fmaf(p, u, 0.2f);
    p = fmaf(p, u, 0.25f);
    p = fmaf(p, u, 0.33333333f);
    p = fmaf(p, u, 0.5f);
    p = fmaf(p, u, 1.0f);
    const float en = (u < 0.125f) ? p * u : enw;
    return fmaf(l, c, -__log2f(en));
}

// Issue batch J: two async 16B nt loads into (LD, UD).  Opaque to the
// compiler: cannot be sunk, registers pinned, no L1 allocation.
#define ISSUE2(LD, UD, J)                                               \
    {                                                                   \
        const int fi = min(t + (J) * TPB, last);                        \
        asm volatile("global_load_dwordx4 %0, %2, off nt\n\t"           \
                     "global_load_dwordx4 %1, %3, off nt"               \
                     : "=&v"(LD), "=&v"(UD)                             \
                     : "v"(lg4 + fi), "v"(nz4 + fi));                   \
    }

// Issue batch J: one async 16B nt load (greedy path, logits only).
#define ISSUE1(LD, J)                                                   \
    {                                                                   \
        const int fi = min(t + (J) * TPB, last);                        \
        asm volatile("global_load_dwordx4 %0, %1, off nt"               \
                     : "=&v"(LD) : "v"(lg4 + fi));                      \
    }

// Counted wait: oldest loads retired, N newest still in flight.  The
// sched_barrier stops the compiler hoisting the consume VALU above the wait.
#define WAITV(N)                                                        \
    asm volatile("s_waitcnt vmcnt(" #N ")" ::: "memory");               \
    __builtin_amdgcn_sched_barrier(0)

// Consume batch JC from (LC, UC) -- sampled path.
#define CONS_S(LC, UC, JC)                                              \
    {                                                                   \
        const int f = t + (JC) * TPB;                                   \
        if (f < V4c) {                                                  \
            const int base = (gbase + f) << 2;                          \
            const float k0 = gumbel_key(LC.x, UC.x, c);                 \
            const float k1 = gumbel_key(LC.y, UC.y, c);                 \
            const float k2 = gumbel_key(LC.z, UC.z, c);                 \
            const float k3 = gumbel_key(LC.w, UC.w, c);                 \
            if (k0 > bv) { bv = k0; bi = base;     }                    \
            if (k1 > bv) { bv = k1; bi = base + 1; }                    \
            if (k2 > bv) { bv = k2; bi = base + 2; }                    \
            if (k3 > bv) { bv = k3; bi = base + 3; }                    \
        }                                                               \
    }

// Consume batch JC -- greedy path.
#define CONS_G(LC, JC)                                                  \
    {                                                                   \
        const int f = t + (JC) * TPB;                                   \
        if (f < V4c) {                                                  \
            const int base = (gbase + f) << 2;                          \
            if (LC.x > bv) { bv = LC.x; bi = base;     }                \
            if (LC.y > bv) { bv = LC.y; bi = base + 1; }                \
            if (LC.z > bv) { bv = LC.z; bi = base + 2; }                \
            if (LC.w > bv) { bv = LC.w; bi = base + 3; }                \
        }                                                               \
    }

__global__ __launch_bounds__(TPB, 8) void sampler_phase1(
    const float* __restrict__ logits,
    const float* __restrict__ temps,
    const float* __restrict__ noise,
    float* __restrict__ ws_val,
    int* __restrict__ ws_idx, int V)
{
    const int chunk = blockIdx.x & (CHUNKS - 1);
    const int b     = blockIdx.x / CHUNKS;
    const int V4    = V >> 2;               // 32064
    const int V4c   = V4 / CHUNKS;          // 4008 (V divisible by 32)
    const int gbase = chunk * V4c;          // this chunk's first float4 index
    const float temp = temps[b];
    const v4f* __restrict__ lg4 =
        (const v4f*)(logits + (size_t)b * V) + gbase;
    const v4f* __restrict__ nz4 =
        (const v4f*)(noise + (size_t)b * V) + gbase;
    const int t    = threadIdx.x;
    const int last = V4c - 1;
    const int NIT  = (V4c + TPB - 1) / TPB;     // 16 for V=128256
    const int NIT4 = (NIT + 3) & ~3;            // pipeline works in groups of 4

    float bv = -INFINITY;
    int   bi = 0x7fffffff;

    if (temp == 0.0f) {
        // Greedy: argmax of raw logits, no noise traffic.
        v4f A0, A1, A2, A3;
        ISSUE1(A0, 0);
        ISSUE1(A1, 1);
        ISSUE1(A2, 2);
        for (int j = 0; j < NIT4; j += 4) {
            ISSUE1(A3, j + 3); WAITV(3); CONS_G(A0, j + 0);
            ISSUE1(A0, j + 4); WAITV(3); CONS_G(A1, j + 1);
            ISSUE1(A1, j + 5); WAITV(3); CONS_G(A2, j + 2);
            ISSUE1(A2, j + 6); WAITV(3); CONS_G(A3, j + 3);
        }
        // Drain; inputs pin buffer registers live until all loads returned.
        asm volatile("s_waitcnt vmcnt(0)"
                     :: "v"(A0), "v"(A1), "v"(A2), "v"(A3) : "memory");
        __builtin_amdgcn_sched_barrier(0);
    } else {
        const float c = (1.0f / temp) * 1.4426950408889634f;  // invT / ln2
        v4f L0, L1, L2, L3, U0, U1, U2, U3;
        ISSUE2(L0, U0, 0);
        ISSUE2(L1, U1, 1);
        ISSUE2(L2, U2, 2);
        for (int j = 0; j < NIT4; j += 4) {
            ISSUE2(L3, U3, j + 3); WAITV(6); CONS_S(L0, U0, j + 0);
            ISSUE2(L0, U0, j + 4); WAITV(6); CONS_S(L1, U1, j + 1);
            ISSUE2(L1, U1, j + 5); WAITV(6); CONS_S(L2, U2, j + 2);
            ISSUE2(L2, U2, j + 6); WAITV(6); CONS_S(L3, U3, j + 3);
        }
        asm volatile("s_waitcnt vmcnt(0)"
                     :: "v"(L0), "v"(U0), "v"(L1), "v"(U1),
                        "v"(L2), "v"(U2), "v"(L3), "v"(U3) : "memory");
        __builtin_amdgcn_sched_barrier(0);
    }

    // wave (64-lane) shuffle reduction, lowest-index tie-break
    #pragma unroll
    for (int off = 32; off > 0; off >>= 1) {
        const float ov = __shfl_down(bv, off);
        const int   oi = __shfl_down(bi, off);
        amax_comb(ov, oi, bv, bi);
    }

    __shared__ float s_v[TPB / 64];
    __shared__ int   s_i[TPB / 64];
    const int lane = t & 63;
    const int wave = t >> 6;
    if (lane == 0) { s_v[wave] = bv; s_i[wave] = bi; }
    __syncthreads();
    if (t == 0) {
        #pragma unroll
        for (int w = 1; w < TPB / 64; ++w) amax_comb(s_v[w], s_i[w], bv, bi);
        ws_val[blockIdx.x] = bv;
        ws_idx[blockIdx.x] = bi;
    }
}

__global__ void sampler_phase2(const float* __restrict__ ws_val,
                               const int* __restrict__ ws_idx,
                               int* __restrict__ out, int B)
{
    const int b = blockIdx.x * blockDim.x + threadIdx.x;
    if (b >= B) return;
    float bv = -INFINITY;
    int   bi = 0x7fffffff;
    #pragma unroll
    for (int c = 0; c < CHUNKS; ++c) {
        const float v = ws_val[b * CHUNKS + c];
        const int   i = ws_idx[b * CHUNKS + c];
        // chunk-ascending iteration + strict-> keeps lowest index on ties
        if (v > bv || (v == bv && i < bi)) { bv = v; bi = i; }
    }
    out[b] = bi;
}

extern "C" void kernel_launch(void* const* d_in, const int* in_sizes, int n_in,
                              void* d_out, int out_size, void* d_ws, size_t ws_size,
                              hipStream_t stream) {
    const float* logits = (const float*)d_in[0];   // [B, V] fp32
    const float* temps  = (const float*)d_in[1];   // [B]    fp32
    const float* noise  = (const float*)d_in[2];   // [B, V] fp32
    int* out = (int*)d_out;                        // [B]    int32
    const int B = in_sizes[1];
    const int V = in_sizes[0] / B;

    float* ws_val = (float*)d_ws;                  // [B*CHUNKS]
    int*   ws_idx = (int*)d_ws + (size_t)B * CHUNKS;

    sampler_phase1<<<B * CHUNKS, TPB, 0, stream>>>(logits, temps, noise,
                                                   ws_val, ws_idx, V);
    sampler_phase2<<<(B + 255) / 256, 256, 0, stream>>>(ws_val, ws_idx, out, B);
}